// Round 1
// baseline (50735.815 us; speedup 1.0000x reference)
//
#include <hip/hip_runtime.h>
#include <hip/hip_bf16.h>

// Problem constants
#define T_STEPS 512
#define BATCH   64
#define IDIM    1024
#define HDIM    1024
#define GDIM    4096   // 4*HDIM

typedef __attribute__((ext_vector_type(8))) short short8;
typedef __attribute__((ext_vector_type(8))) unsigned short ushort8;
typedef __attribute__((ext_vector_type(4))) float f32x4;

static __device__ __forceinline__ unsigned short f2bf(float f) {
    union { float f; unsigned u; } x; x.f = f;
    unsigned r = x.u + 0x7fffu + ((x.u >> 16) & 1u);  // round-to-nearest-even
    return (unsigned short)(r >> 16);
}

// ---------------------------------------------------------------------------
// Kernel 0: convert h0 (fp32 [B,H]) -> bf16 buffer 0
// ---------------------------------------------------------------------------
__global__ void k_h0_to_bf16(const float* __restrict__ h0,
                             unsigned short* __restrict__ hbuf0) {
    int i = blockIdx.x * 256 + threadIdx.x;   // grid covers exactly B*H = 65536
    hbuf0[i] = f2bf(h0[i]);
}

// ---------------------------------------------------------------------------
// Kernel 1: gx = input @ W_x^T + b_x + b_h     (fp32 in, bf16 MFMA, fp32 out)
// A = input [32768,1024] row-major; B = W_x [4096,1024] row-major (B^T GEMM)
// 128x128 tile, BK=32, 4 waves, each wave 64x64 (4x4 fragments of 16x16x32)
// ---------------------------------------------------------------------------
__global__ __launch_bounds__(256) void k_gx_gemm(
        const float* __restrict__ X, const float* __restrict__ Wx,
        const float* __restrict__ bx, const float* __restrict__ bh,
        float* __restrict__ gx) {
    __shared__ unsigned short As[128][40];   // +8 pad: 2-way (free) bank access
    __shared__ unsigned short Bs[128][40];

    const int bid  = blockIdx.x;
    const int nt   = bid & 31;     // 32 N tiles
    const int mt   = bid >> 5;     // 256 M tiles
    const int tid  = threadIdx.x;
    const int lane = tid & 63;
    const int w    = tid >> 6;
    const int wm   = (w >> 1) * 64;
    const int wn   = (w & 1) * 64;
    const int lmod = lane & 15;
    const int lk8  = (lane >> 4) * 8;

    f32x4 acc[4][4] = {};

    const int srow = tid >> 1;            // 0..127
    const int scol = (tid & 1) * 16;      // 0 or 16
    const float* Abase = X  + (size_t)(mt * 128 + srow) * 1024 + scol;
    const float* Bbase = Wx + (size_t)(nt * 128 + srow) * 1024 + scol;

    for (int k0 = 0; k0 < 1024; k0 += 32) {
        // ---- stage A/B tile (fp32 -> bf16 in registers, then LDS) ----
        const float4* a4 = reinterpret_cast<const float4*>(Abase + k0);
        const float4* b4 = reinterpret_cast<const float4*>(Bbase + k0);
        ushort8 pa[2], pb[2];
#pragma unroll
        for (int h = 0; h < 2; ++h) {
            float4 v0 = a4[h * 2], v1 = a4[h * 2 + 1];
            ushort8 t;
            t[0]=f2bf(v0.x); t[1]=f2bf(v0.y); t[2]=f2bf(v0.z); t[3]=f2bf(v0.w);
            t[4]=f2bf(v1.x); t[5]=f2bf(v1.y); t[6]=f2bf(v1.z); t[7]=f2bf(v1.w);
            pa[h] = t;
            float4 u0 = b4[h * 2], u1 = b4[h * 2 + 1];
            ushort8 s;
            s[0]=f2bf(u0.x); s[1]=f2bf(u0.y); s[2]=f2bf(u0.z); s[3]=f2bf(u0.w);
            s[4]=f2bf(u1.x); s[5]=f2bf(u1.y); s[6]=f2bf(u1.z); s[7]=f2bf(u1.w);
            pb[h] = s;
        }
        __syncthreads();   // previous iteration's fragment reads done
        *reinterpret_cast<ushort8*>(&As[srow][scol])     = pa[0];
        *reinterpret_cast<ushort8*>(&As[srow][scol + 8]) = pa[1];
        *reinterpret_cast<ushort8*>(&Bs[srow][scol])     = pb[0];
        *reinterpret_cast<ushort8*>(&Bs[srow][scol + 8]) = pb[1];
        __syncthreads();

        // ---- fragments + 16 MFMA ----
        short8 af[4], bf_[4];
#pragma unroll
        for (int i = 0; i < 4; ++i)
            af[i] = *reinterpret_cast<const short8*>(&As[wm + i * 16 + lmod][lk8]);
#pragma unroll
        for (int i = 0; i < 4; ++i)
            bf_[i] = *reinterpret_cast<const short8*>(&Bs[wn + i * 16 + lmod][lk8]);
#pragma unroll
        for (int i = 0; i < 4; ++i)
#pragma unroll
            for (int j = 0; j < 4; ++j)
                acc[i][j] = __builtin_amdgcn_mfma_f32_16x16x32_bf16(
                                af[i], bf_[j], acc[i][j], 0, 0, 0);
    }

    // ---- epilogue: += (b_x + b_h), write fp32 gx ----
#pragma unroll
    for (int j = 0; j < 4; ++j) {
        int n = nt * 128 + wn + j * 16 + lmod;
        float bb = bx[n] + bh[n];
#pragma unroll
        for (int i = 0; i < 4; ++i) {
            int mbase = mt * 128 + wm + i * 16 + (lane >> 4) * 4;
#pragma unroll
            for (int r = 0; r < 4; ++r)
                gx[(size_t)(mbase + r) * GDIM + n] = acc[i][j][r] + bb;
        }
    }
}

// ---------------------------------------------------------------------------
// Kernel 2: persistent LSTM recurrence.
// 256 blocks x 512 threads. Block b owns hidden units [b*4, b*4+4).
// LDS holds the 16 W_h rows (4 units x 4 gates) as bf16, K-contiguous.
// h double-buffered in ws as bf16; c in registers (threads 0..255).
// One device-scope grid barrier per step.
// ---------------------------------------------------------------------------
__global__ __launch_bounds__(512) void k_lstm(
        const float* __restrict__ gx, const float* __restrict__ Wh,
        const float* __restrict__ c0, float* __restrict__ out,
        unsigned short* __restrict__ hbuf, unsigned* __restrict__ bar) {
    __shared__ unsigned short Wl[16][1032];   // +8 pad
    __shared__ float gs[2][64][16];           // per-K-half partial sums

    const int b    = blockIdx.x;     // 256
    const int tid  = threadIdx.x;    // 512
    const int lane = tid & 63;
    const int w    = tid >> 6;       // 0..7

    // ---- load W_h slice -> LDS bf16. local col n = ul*4 + g  (ul=n>>2, g=n&3)
    {
        int n    = tid >> 5;           // 0..15
        int cg   = (tid & 31) * 32;    // 32 cols per thread
        int wrow = (n & 3) * HDIM + b * 4 + (n >> 2);
        const float* src = Wh + (size_t)wrow * HDIM + cg;
#pragma unroll
        for (int j = 0; j < 32; j += 4) {
            float4 v = *reinterpret_cast<const float4*>(src + j);
            Wl[n][cg + j + 0] = f2bf(v.x);
            Wl[n][cg + j + 1] = f2bf(v.y);
            Wl[n][cg + j + 2] = f2bf(v.z);
            Wl[n][cg + j + 3] = f2bf(v.w);
        }
    }

    // ---- c state in registers (threads 0..255: one (batch, unit) pair each)
    float c_reg = 0.f;
    const int gm = tid >> 2;       // batch
    const int gu = tid & 3;        // local unit
    const int uglob = b * 4 + gu;
    if (tid < 256) c_reg = c0[gm * HDIM + uglob];
    __syncthreads();

    const int khalf = w >> 2;                 // 0/1: K in [0,512) or [512,1024)
    const int m0    = (w & 3) * 16;           // 16-row batch tile per wave
    const int arow  = m0 + (lane & 15);
    const int kfrag = khalf * 512 + (lane >> 4) * 8;
    const int drow  = m0 + (lane >> 4) * 4;   // D-frag base row
    const int dcol  = lane & 15;

    for (int t = 0; t < T_STEPS; ++t) {
        const unsigned short* hin = hbuf + (size_t)(t & 1) * BATCH * HDIM;

        // ---- recurrent GEMM: g_part[64x16] over this wave's K half ----
        f32x4 acc = {};
        const unsigned short* hp = hin + (size_t)arow * HDIM + kfrag;
        const unsigned short* wp = &Wl[lane & 15][kfrag];
#pragma unroll
        for (int ks = 0; ks < 16; ++ks) {
            short8 av = *reinterpret_cast<const short8*>(hp + ks * 32);
            short8 bv = *reinterpret_cast<const short8*>(wp + ks * 32);
            acc = __builtin_amdgcn_mfma_f32_16x16x32_bf16(av, bv, acc, 0, 0, 0);
        }
#pragma unroll
        for (int r = 0; r < 4; ++r)
            gs[khalf][drow + r][dcol] = acc[r];
        __syncthreads();

        // ---- gates + state update (threads 0..255) ----
        if (tid < 256) {
            const float* gxr = gx + ((size_t)t * BATCH + gm) * GDIM + uglob;
            float xi = gxr[0]        + gs[0][gm][gu * 4 + 0] + gs[1][gm][gu * 4 + 0];
            float xf = gxr[HDIM]     + gs[0][gm][gu * 4 + 1] + gs[1][gm][gu * 4 + 1];
            float xo = gxr[2 * HDIM] + gs[0][gm][gu * 4 + 2] + gs[1][gm][gu * 4 + 2];
            float xn = gxr[3 * HDIM] + gs[0][gm][gu * 4 + 3] + gs[1][gm][gu * 4 + 3];
            float ig = 1.f / (1.f + expf(-xi));
            float fg = 1.f / (1.f + expf(-xf));
            float og = 1.f / (1.f + expf(-xo));
            float ng = tanhf(xn);
            c_reg = fg * c_reg + ig * ng;
            float h = og * tanhf(c_reg);
            out[((size_t)t * BATCH + gm) * HDIM + uglob] = h;
            hbuf[(size_t)((t + 1) & 1) * BATCH * HDIM + gm * HDIM + uglob] = f2bf(h);
            if (t == T_STEPS - 1) {
                size_t fin = (size_t)T_STEPS * BATCH * HDIM;
                out[fin + gm * HDIM + uglob] = h;                    // h_fin
                out[fin + BATCH * HDIM + gm * HDIM + uglob] = c_reg; // c_fin
            }
        }

        // ---- grid barrier (all blocks advance to step t+1 together) ----
        __threadfence();      // make h writes visible at agent scope
        __syncthreads();
        if (tid == 0) {
            __hip_atomic_fetch_add(bar, 1u, __ATOMIC_RELAXED,
                                   __HIP_MEMORY_SCOPE_AGENT);
            unsigned tgt = (unsigned)(t + 1) * gridDim.x;
            while (__hip_atomic_load(bar, __ATOMIC_RELAXED,
                                     __HIP_MEMORY_SCOPE_AGENT) < tgt) {
                __builtin_amdgcn_s_sleep(2);
            }
        }
        __syncthreads();
        __threadfence();      // acquire: discard stale h lines
    }
}

// ---------------------------------------------------------------------------
extern "C" void kernel_launch(void* const* d_in, const int* in_sizes, int n_in,
                              void* d_out, int out_size, void* d_ws, size_t ws_size,
                              hipStream_t stream) {
    const float* X  = (const float*)d_in[0];
    const float* h0 = (const float*)d_in[1];
    const float* c0 = (const float*)d_in[2];
    const float* Wx = (const float*)d_in[3];
    const float* Wh = (const float*)d_in[4];
    const float* bx = (const float*)d_in[5];
    const float* bh = (const float*)d_in[6];
    float* out = (float*)d_out;

    char* ws = (char*)d_ws;
    float* gx = (float*)ws;                                   // 512 MB fp32
    size_t gx_bytes = (size_t)T_STEPS * BATCH * GDIM * 4;
    unsigned short* hbuf = (unsigned short*)(ws + gx_bytes);  // 256 KB bf16 x2
    size_t hbuf_bytes = (size_t)2 * BATCH * HDIM * 2;
    unsigned* bar = (unsigned*)(ws + gx_bytes + hbuf_bytes);

    hipMemsetAsync(bar, 0, 256, stream);
    k_h0_to_bf16<<<dim3(256), dim3(256), 0, stream>>>(h0, hbuf);
    k_gx_gemm<<<dim3(8192), dim3(256), 0, stream>>>(X, Wx, bx, bh, gx);
    k_lstm<<<dim3(256), dim3(512), 0, stream>>>(gx, Wh, c0, out, hbuf, bar);
}

// Round 2
// 11505.149 us; speedup vs baseline: 4.4098x; 4.4098x over previous
//
#include <hip/hip_runtime.h>
#include <hip/hip_bf16.h>

// Problem constants
#define T_STEPS 512
#define BATCH   64
#define IDIM    1024
#define HDIM    1024
#define GDIM    4096   // 4*HDIM
#define UPB     16     // hidden units per recurrence block
#define LSTM_BLOCKS 64 // HDIM / UPB

typedef __attribute__((ext_vector_type(8))) short short8;
typedef __attribute__((ext_vector_type(8))) unsigned short ushort8;
typedef __attribute__((ext_vector_type(4))) float f32x4;

static __device__ __forceinline__ unsigned short f2bf(float f) {
    union { float f; unsigned u; } x; x.f = f;
    unsigned r = x.u + 0x7fffu + ((x.u >> 16) & 1u);  // round-to-nearest-even
    return (unsigned short)(r >> 16);
}

// ---------------------------------------------------------------------------
// Kernel 0: convert h0 (fp32 [B,H]) -> bf16 buffer 0
// ---------------------------------------------------------------------------
__global__ void k_h0_to_bf16(const float* __restrict__ h0,
                             unsigned short* __restrict__ hbuf0) {
    int i = blockIdx.x * 256 + threadIdx.x;   // grid covers exactly B*H = 65536
    hbuf0[i] = f2bf(h0[i]);
}

// ---------------------------------------------------------------------------
// Kernel 1: gx = input @ W_x^T + b_x + b_h     (fp32 in, bf16 MFMA, fp32 out)
// Unchanged from round 1 (passed; ~600 us).
// ---------------------------------------------------------------------------
__global__ __launch_bounds__(256) void k_gx_gemm(
        const float* __restrict__ X, const float* __restrict__ Wx,
        const float* __restrict__ bx, const float* __restrict__ bh,
        float* __restrict__ gx) {
    __shared__ unsigned short As[128][40];
    __shared__ unsigned short Bs[128][40];

    const int bid  = blockIdx.x;
    const int nt   = bid & 31;     // 32 N tiles
    const int mt   = bid >> 5;     // 256 M tiles
    const int tid  = threadIdx.x;
    const int lane = tid & 63;
    const int w    = tid >> 6;
    const int wm   = (w >> 1) * 64;
    const int wn   = (w & 1) * 64;
    const int lmod = lane & 15;
    const int lk8  = (lane >> 4) * 8;

    f32x4 acc[4][4] = {};

    const int srow = tid >> 1;
    const int scol = (tid & 1) * 16;
    const float* Abase = X  + (size_t)(mt * 128 + srow) * 1024 + scol;
    const float* Bbase = Wx + (size_t)(nt * 128 + srow) * 1024 + scol;

    for (int k0 = 0; k0 < 1024; k0 += 32) {
        const float4* a4 = reinterpret_cast<const float4*>(Abase + k0);
        const float4* b4 = reinterpret_cast<const float4*>(Bbase + k0);
        ushort8 pa[2], pb[2];
#pragma unroll
        for (int h = 0; h < 2; ++h) {
            float4 v0 = a4[h * 2], v1 = a4[h * 2 + 1];
            ushort8 t;
            t[0]=f2bf(v0.x); t[1]=f2bf(v0.y); t[2]=f2bf(v0.z); t[3]=f2bf(v0.w);
            t[4]=f2bf(v1.x); t[5]=f2bf(v1.y); t[6]=f2bf(v1.z); t[7]=f2bf(v1.w);
            pa[h] = t;
            float4 u0 = b4[h * 2], u1 = b4[h * 2 + 1];
            ushort8 s;
            s[0]=f2bf(u0.x); s[1]=f2bf(u0.y); s[2]=f2bf(u0.z); s[3]=f2bf(u0.w);
            s[4]=f2bf(u1.x); s[5]=f2bf(u1.y); s[6]=f2bf(u1.z); s[7]=f2bf(u1.w);
            pb[h] = s;
        }
        __syncthreads();
        *reinterpret_cast<ushort8*>(&As[srow][scol])     = pa[0];
        *reinterpret_cast<ushort8*>(&As[srow][scol + 8]) = pa[1];
        *reinterpret_cast<ushort8*>(&Bs[srow][scol])     = pb[0];
        *reinterpret_cast<ushort8*>(&Bs[srow][scol + 8]) = pb[1];
        __syncthreads();

        short8 af[4], bf_[4];
#pragma unroll
        for (int i = 0; i < 4; ++i)
            af[i] = *reinterpret_cast<const short8*>(&As[wm + i * 16 + lmod][lk8]);
#pragma unroll
        for (int i = 0; i < 4; ++i)
            bf_[i] = *reinterpret_cast<const short8*>(&Bs[wn + i * 16 + lmod][lk8]);
#pragma unroll
        for (int i = 0; i < 4; ++i)
#pragma unroll
            for (int j = 0; j < 4; ++j)
                acc[i][j] = __builtin_amdgcn_mfma_f32_16x16x32_bf16(
                                af[i], bf_[j], acc[i][j], 0, 0, 0);
    }

#pragma unroll
    for (int j = 0; j < 4; ++j) {
        int n = nt * 128 + wn + j * 16 + lmod;
        float bb = bx[n] + bh[n];
#pragma unroll
        for (int i = 0; i < 4; ++i) {
            int mbase = mt * 128 + wm + i * 16 + (lane >> 4) * 4;
#pragma unroll
            for (int r = 0; r < 4; ++r)
                gx[(size_t)(mbase + r) * GDIM + n] = acc[i][j][r] + bb;
        }
    }
}

// ---------------------------------------------------------------------------
// Kernel 2: persistent LSTM recurrence.
// 64 blocks x 256 threads (4 waves). Block b owns hidden units [b*16, b*16+16)
// = 64 gate-columns. W_h slice (64 x 1024) resident in LDS as bf16 (132 KB ->
// 1 block/CU, 64 blocks always co-resident: grid barrier deadlock-safe).
// Grid barrier = per-block flag array (release store + wave-0 ballot poll),
// no atomic RMW contention. gx for step t+1 prefetched into registers during
// the poll.
// ---------------------------------------------------------------------------
__global__ __launch_bounds__(256, 1) void k_lstm(
        const float* __restrict__ gx, const float* __restrict__ Wh,
        const float* __restrict__ cinit, float* __restrict__ out,
        unsigned short* __restrict__ hbuf, unsigned* __restrict__ bar) {
    __shared__ __align__(16) unsigned short Wl[64][1032]; // pad: 2-way (free)
    __shared__ __align__(16) float gs[64][68];            // pad: 2-way (free)

    const int b    = blockIdx.x;     // 64
    const int tid  = threadIdx.x;    // 256
    const int lane = tid & 63;
    const int w    = tid >> 6;       // 0..3

    // ---- W_h slice -> LDS bf16. Local col n <-> W_h row (n>>4)*H + b*16 + (n&15)
    {
        const int n    = tid >> 2;            // 0..63
        const int cseg = (tid & 3) * 256;     // K segment
        const int wrow = (n >> 4) * HDIM + b * UPB + (n & 15);
        const float* src = Wh + (size_t)wrow * HDIM + cseg;
#pragma unroll 4
        for (int j = 0; j < 256; j += 4) {
            float4 v = *reinterpret_cast<const float4*>(src + j);
            Wl[n][cseg + j + 0] = f2bf(v.x);
            Wl[n][cseg + j + 1] = f2bf(v.y);
            Wl[n][cseg + j + 2] = f2bf(v.z);
            Wl[n][cseg + j + 3] = f2bf(v.w);
        }
    }

    // ---- per-thread gate ownership: unit u, batch rows mg*4..mg*4+3
    const int u   = tid & 15;
    const int mg  = tid >> 4;        // 0..15
    const int col = b * UPB + u;     // global hidden index

    float c_reg[4];
#pragma unroll
    for (int r = 0; r < 4; ++r)
        c_reg[r] = cinit[(size_t)(mg * 4 + r) * HDIM + col];

    // gx for t=0
    float gxv[4][4];
#pragma unroll
    for (int r = 0; r < 4; ++r)
#pragma unroll
        for (int g = 0; g < 4; ++g)
            gxv[r][g] = gx[(size_t)(mg * 4 + r) * GDIM + g * HDIM + col];

    __syncthreads();

    // ---- wave tile: 2x2 waves, each 32x32 output, full K
    const int wm  = (w & 1) * 32;
    const int wn  = (w >> 1) * 32;
    const int l15 = lane & 15;
    const int lk  = (lane >> 4) * 8;
    const unsigned short* wp0 = &Wl[wn + l15][lk];
    const unsigned short* wp1 = &Wl[wn + 16 + l15][lk];

    for (int t = 0; t < T_STEPS; ++t) {
        const unsigned short* hin = hbuf + (size_t)(t & 1) * BATCH * HDIM;
        const unsigned short* hp0 = hin + (size_t)(wm + l15) * HDIM + lk;
        const unsigned short* hp1 = hp0 + (size_t)16 * HDIM;

        f32x4 acc00 = {}, acc01 = {}, acc10 = {}, acc11 = {};
#pragma unroll
        for (int ks = 0; ks < 32; ++ks) {
            short8 a0 = *reinterpret_cast<const short8*>(hp0 + ks * 32);
            short8 a1 = *reinterpret_cast<const short8*>(hp1 + ks * 32);
            short8 b0 = *reinterpret_cast<const short8*>(wp0 + ks * 32);
            short8 b1 = *reinterpret_cast<const short8*>(wp1 + ks * 32);
            acc00 = __builtin_amdgcn_mfma_f32_16x16x32_bf16(a0, b0, acc00, 0, 0, 0);
            acc01 = __builtin_amdgcn_mfma_f32_16x16x32_bf16(a0, b1, acc01, 0, 0, 0);
            acc10 = __builtin_amdgcn_mfma_f32_16x16x32_bf16(a1, b0, acc10, 0, 0, 0);
            acc11 = __builtin_amdgcn_mfma_f32_16x16x32_bf16(a1, b1, acc11, 0, 0, 0);
        }
        {
            const int gr = (lane >> 4) * 4;
#pragma unroll
            for (int r = 0; r < 4; ++r) {
                gs[wm + gr + r][wn + l15]           = acc00[r];
                gs[wm + gr + r][wn + 16 + l15]      = acc01[r];
                gs[wm + 16 + gr + r][wn + l15]      = acc10[r];
                gs[wm + 16 + gr + r][wn + 16 + l15] = acc11[r];
            }
        }
        __syncthreads();

        // ---- gates + state update (all 256 threads, 4 batch rows each)
        unsigned short* hout = hbuf + (size_t)((t + 1) & 1) * BATCH * HDIM;
        float hv[4];
#pragma unroll
        for (int r = 0; r < 4; ++r) {
            const int m = mg * 4 + r;
            float xi = gxv[r][0] + gs[m][u];
            float xf = gxv[r][1] + gs[m][16 + u];
            float xo = gxv[r][2] + gs[m][32 + u];
            float xn = gxv[r][3] + gs[m][48 + u];
            float ig = 1.f / (1.f + expf(-xi));
            float fg = 1.f / (1.f + expf(-xf));
            float og = 1.f / (1.f + expf(-xo));
            float ng = tanhf(xn);
            c_reg[r] = fg * c_reg[r] + ig * ng;
            float h = og * tanhf(c_reg[r]);
            hv[r] = h;
            out[((size_t)t * BATCH + m) * HDIM + col] = h;
            hout[(size_t)m * HDIM + col] = f2bf(h);
        }

        if (t == T_STEPS - 1) {
            size_t fin = (size_t)T_STEPS * BATCH * HDIM;
#pragma unroll
            for (int r = 0; r < 4; ++r) {
                const int m = mg * 4 + r;
                out[fin + (size_t)m * HDIM + col] = hv[r];                     // h_fin
                out[fin + (size_t)BATCH * HDIM + (size_t)m * HDIM + col] = c_reg[r]; // c_fin
            }
            break;   // no barrier needed after the last step
        }

        // ---- release: h writes visible at agent scope, then set own flag
        __threadfence();
        __syncthreads();
        if (tid == 0)
            __hip_atomic_store(&bar[b * 32], (unsigned)(t + 1),
                               __ATOMIC_RELAXED, __HIP_MEMORY_SCOPE_AGENT);

        // ---- prefetch gx[t+1] into registers (in flight during the poll)
        {
            const float* gp = gx + (size_t)(t + 1) * BATCH * GDIM;
#pragma unroll
            for (int r = 0; r < 4; ++r)
#pragma unroll
                for (int g = 0; g < 4; ++g)
                    gxv[r][g] = gp[(size_t)(mg * 4 + r) * GDIM + g * HDIM + col];
        }

        // ---- wave 0 polls all 64 flags (one load + ballot per round)
        if (w == 0) {
            const unsigned tgt = (unsigned)(t + 1);
            while (true) {
                unsigned v = __hip_atomic_load(&bar[lane * 32],
                                               __ATOMIC_RELAXED,
                                               __HIP_MEMORY_SCOPE_AGENT);
                if (__all((int)(v >= tgt))) break;
                __builtin_amdgcn_s_sleep(2);
            }
        }
        __syncthreads();
        __threadfence();   // acquire: discard stale h lines before next step
    }
}

// ---------------------------------------------------------------------------
extern "C" void kernel_launch(void* const* d_in, const int* in_sizes, int n_in,
                              void* d_out, int out_size, void* d_ws, size_t ws_size,
                              hipStream_t stream) {
    const float* X  = (const float*)d_in[0];
    const float* h0 = (const float*)d_in[1];
    const float* c0 = (const float*)d_in[2];
    const float* Wx = (const float*)d_in[3];
    const float* Wh = (const float*)d_in[4];
    const float* bx = (const float*)d_in[5];
    const float* bh = (const float*)d_in[6];
    float* out = (float*)d_out;

    char* ws = (char*)d_ws;
    float* gx = (float*)ws;                                   // 512 MB fp32
    size_t gx_bytes = (size_t)T_STEPS * BATCH * GDIM * 4;
    unsigned short* hbuf = (unsigned short*)(ws + gx_bytes);  // 256 KB bf16 x2
    size_t hbuf_bytes = (size_t)2 * BATCH * HDIM * 2;
    unsigned* bar = (unsigned*)(ws + gx_bytes + hbuf_bytes);  // 64 flags, 128B apart

    hipMemsetAsync(bar, 0, LSTM_BLOCKS * 32 * sizeof(unsigned), stream);
    k_h0_to_bf16<<<dim3(256), dim3(256), 0, stream>>>(h0, hbuf);
    k_gx_gemm<<<dim3(8192), dim3(256), 0, stream>>>(X, Wx, bx, bh, gx);
    k_lstm<<<dim3(LSTM_BLOCKS), dim3(256), 0, stream>>>(gx, Wh, c0, out, hbuf, bar);
}